// Round 1
// baseline (2507.733 us; speedup 1.0000x reference)
//
#include <hip/hip_runtime.h>

// ---------------------------------------------------------------------------
// LavaNetwork: x(32,512,1024) -> GEMM(w1 2048x512)+b1 -> LIF -> spk1
//                              -> GEMM(w2 256x2048)+b2 -> LIF -> spk2
// cur written into d_out regions, LIF scan converts cur->spikes in place.
// GEMM fp32, LIF voltage recurrence in double (matches np f64 reference
// semantics; only residual error = fp32 rounding of cur).
// ---------------------------------------------------------------------------

#define BM 64
#define BN 64
#define BK 16
#define TM 4
#define TN 4

__global__ __launch_bounds__(256) void gemm_bias_kernel(
    const float* __restrict__ A,     // (M,K) row-major, shared across batch
    const float* __restrict__ Bmat,  // (K,N) row-major, batch stride sB
    const float* __restrict__ bias,  // (M)
    float* __restrict__ C,           // (M,N), batch stride sC
    int M, int N, int K, long sB, long sC)
{
    __shared__ float As[BK][BM + 1];
    __shared__ float Bs[BK][BN + 1];

    const int batch = blockIdx.z;
    const float* Bp = Bmat + (long)batch * sB;
    float* Cp = C + (long)batch * sC;

    const int m0 = blockIdx.y * BM;
    const int n0 = blockIdx.x * BN;
    const int tid = threadIdx.x;

    const int tcol = tid % (BN / TN);  // 0..15
    const int trow = tid / (BN / TN);  // 0..15

    float acc[TM][TN];
#pragma unroll
    for (int i = 0; i < TM; i++)
#pragma unroll
        for (int j = 0; j < TN; j++) acc[i][j] = 0.f;

    // staging index split
    const int a_k = tid % BK;   // 0..15
    const int a_m = tid / BK;   // 0..15 (x4 passes)
    const int b_n = tid % BN;   // 0..63
    const int b_k = tid / BN;   // 0..3  (x4 passes)

    for (int k0 = 0; k0 < K; k0 += BK) {
#pragma unroll
        for (int i = 0; i < BM; i += 16)
            As[a_k][a_m + i] = A[(long)(m0 + a_m + i) * K + k0 + a_k];
#pragma unroll
        for (int i = 0; i < BK; i += 4)
            Bs[b_k + i][b_n] = Bp[(long)(k0 + b_k + i) * N + n0 + b_n];
        __syncthreads();

#pragma unroll
        for (int kk = 0; kk < BK; kk++) {
            float ar[TM], br[TN];
#pragma unroll
            for (int i = 0; i < TM; i++) ar[i] = As[kk][trow * TM + i];
#pragma unroll
            for (int j = 0; j < TN; j++) br[j] = Bs[kk][tcol * TN + j];
#pragma unroll
            for (int i = 0; i < TM; i++)
#pragma unroll
                for (int j = 0; j < TN; j++) acc[i][j] += ar[i] * br[j];
        }
        __syncthreads();
    }

#pragma unroll
    for (int i = 0; i < TM; i++) {
        const float bv = bias[m0 + trow * TM + i];
#pragma unroll
        for (int j = 0; j < TN; j++) {
            Cp[(long)(m0 + trow * TM + i) * N + n0 + tcol * TN + j] =
                acc[i][j] + bv;
        }
    }
}

// In-place CUBA-LIF scan: data rows are (row, T) currents; overwritten with
// binary spikes. Voltage recurrence in double to match f64 reference exactly
// (beta = f64(0.95), threshold compare in f64, reset-to-zero).
__global__ __launch_bounds__(256) void lif_kernel(float* __restrict__ data,
                                                  long nrows, int T)
{
    long r = (long)blockIdx.x * blockDim.x + threadIdx.x;
    if (r >= nrows) return;
    float* p = data + r * (long)T;
    double v = 0.0;
    for (int t = 0; t < T; t += 4) {
        float4 c = *(float4*)(p + t);
        float4 s;
        v = 0.95 * v + (double)c.x;
        s.x = (v >= 1.0) ? 1.f : 0.f; if (v >= 1.0) v = 0.0;
        v = 0.95 * v + (double)c.y;
        s.y = (v >= 1.0) ? 1.f : 0.f; if (v >= 1.0) v = 0.0;
        v = 0.95 * v + (double)c.z;
        s.z = (v >= 1.0) ? 1.f : 0.f; if (v >= 1.0) v = 0.0;
        v = 0.95 * v + (double)c.w;
        s.w = (v >= 1.0) ? 1.f : 0.f; if (v >= 1.0) v = 0.0;
        *(float4*)(p + t) = s;
    }
}

extern "C" void kernel_launch(void* const* d_in, const int* in_sizes, int n_in,
                              void* d_out, int out_size, void* d_ws, size_t ws_size,
                              hipStream_t stream)
{
    const float* x  = (const float*)d_in[0];  // (32, 512, 1024)
    const float* w1 = (const float*)d_in[1];  // (2048, 512)
    const float* b1 = (const float*)d_in[2];  // (2048)
    const float* w2 = (const float*)d_in[3];  // (256, 2048)
    const float* b2 = (const float*)d_in[4];  // (256)

    float* out  = (float*)d_out;
    float* spk1 = out;                              // (32, 2048, 1024)
    float* spk2 = out + (long)32 * 2048 * 1024;     // (32, 256, 1024)

    // layer 1: cur1 = w1 @ x[b] + b1  -> spk1 region
    {
        dim3 grid(1024 / BN, 2048 / BM, 32);
        gemm_bias_kernel<<<grid, 256, 0, stream>>>(
            w1, x, b1, spk1, 2048, 1024, 512,
            (long)512 * 1024, (long)2048 * 1024);
    }
    // LIF over 32*2048 rows, in place
    lif_kernel<<<(65536 + 255) / 256, 256, 0, stream>>>(spk1, 65536, 1024);

    // layer 2: cur2 = w2 @ spk1[b] + b2 -> spk2 region
    {
        dim3 grid(1024 / BN, 256 / BM, 32);
        gemm_bias_kernel<<<grid, 256, 0, stream>>>(
            w2, spk1, b2, spk2, 256, 1024, 2048,
            (long)2048 * 1024, (long)256 * 1024);
    }
    lif_kernel<<<(8192 + 255) / 256, 256, 0, stream>>>(spk2, 8192, 1024);
}

// Round 3
// 1496.489 us; speedup vs baseline: 1.6757x; 1.6757x over previous
//
#include <hip/hip_runtime.h>

// ---------------------------------------------------------------------------
// LavaNetwork, bit-exact GEMM via 3-plane exact-grid f16 MFMA.
//   w = q0*2^-12 + q1*2^-23 + q2*2^-34, each plane an integer <=2^11 times a
//   power of two => exact in f16 (planes 1,2 stored pre-scaled by 2^11, 2^21
//   to avoid f16 subnormals). Activations are {0,1} (exact in f16).
//   All MFMA fp32 partial sums are integers*grid < 2^24 => EXACT accumulation.
//   Plane sums combined in f64 in epilogue. Only error: final f32 cur store
//   (~1e-7), which round 1's passing fp32 kernel shared.
// cur written to d_out regions; LIF scan (f64 recurrence) converts in place.
// ---------------------------------------------------------------------------

typedef _Float16 f16x8 __attribute__((ext_vector_type(8)));
typedef _Float16 f16x4 __attribute__((ext_vector_type(4)));
typedef float f32x4 __attribute__((ext_vector_type(4)));

// Exact 3-plane split. q0 = w on grid 2^-12 (|w|<0.4998 required; weights are
// N(0,~0.044) so 11 sigma). q1 holds grid-2^-23 residual scaled by 2^11,
// q2 holds grid-2^-34 residual scaled by 2^21. All subtractions Sterbenz-exact.
__device__ inline void split3(float w, _Float16& q0, _Float16& q1, _Float16& q2) {
    float p0 = rintf(w * 4096.f) * 2.44140625e-4f;            // k0 * 2^-12
    float r1 = w - p0;                                         // exact, |r1|<=2^-13
    float p1s = rintf(r1 * 8388608.f) * 2.44140625e-4f;        // k1 * 2^-12 (=p1*2^11)
    float r2 = r1 - p1s * 4.8828125e-4f;                       // exact, |r2|<=2^-24
    float p2s = rintf(r2 * 1.7179869184e10f) * 1.220703125e-4f;// k2 * 2^-13 (=p2*2^21)
    q0 = (_Float16)p0;
    q1 = (_Float16)p1s;
    q2 = (_Float16)p2s;
}

__global__ __launch_bounds__(256) void gemm_f16x3_kernel(
    const float* __restrict__ A,     // (M,K) weights, shared across batch
    const float* __restrict__ Bmat,  // (K,N) fp32 binary activations, stride sB
    const float* __restrict__ bias,  // (M)
    float* __restrict__ C,           // (M,N), stride sC
    int M, int N, int K, long sB, long sC)
{
    __shared__ _Float16 As[3][128][40];   // 3 planes, row pad 32->40 (80 B)
    __shared__ _Float16 Bs[128][40];      // [n][k] transposed

    const int batch = blockIdx.z;
    const float* Bp = Bmat + (long)batch * sB;
    float* Cp = C + (long)batch * sC;

    const int m0 = blockIdx.y * 128;
    const int n0 = blockIdx.x * 128;
    const int tid = threadIdx.x;
    const int lane = tid & 63;
    const int wave = tid >> 6;
    const int wrow = (wave >> 1) * 64;
    const int wcol = (wave & 1) * 64;
    const int lm = lane & 15;       // A-row / B-col within 16
    const int lq = lane >> 4;       // k-octet / C row-quad

    // A staging: thread reads 4 float4s (coalesced)
    const int a_mo = tid >> 3;            // 0..31, + i*32
    const int a_kc = (tid & 7) * 4;       // 0..28
    // B staging: transpose-pack, thread owns 4k x 4n chunk
    const int b_kq = tid >> 5;            // 0..7
    const int b_nq = tid & 31;            // 0..31

    f32x4 acc[3][4][4];
#pragma unroll
    for (int p = 0; p < 3; p++)
#pragma unroll
        for (int i = 0; i < 4; i++)
#pragma unroll
            for (int j = 0; j < 4; j++) acc[p][i][j] = (f32x4)0.f;

    for (int k0 = 0; k0 < K; k0 += 32) {
        // ---- stage A (weights) with exact 3-plane split ----
#pragma unroll
        for (int i = 0; i < 4; i++) {
            const int m = i * 32 + a_mo;
            float4 w = *(const float4*)&A[(long)(m0 + m) * K + k0 + a_kc];
            _Float16 a0[4], a1[4], a2[4];
            split3(w.x, a0[0], a1[0], a2[0]);
            split3(w.y, a0[1], a1[1], a2[1]);
            split3(w.z, a0[2], a1[2], a2[2]);
            split3(w.w, a0[3], a1[3], a2[3]);
            f16x4 v0 = {a0[0], a0[1], a0[2], a0[3]};
            f16x4 v1 = {a1[0], a1[1], a1[2], a1[3]};
            f16x4 v2 = {a2[0], a2[1], a2[2], a2[3]};
            *(f16x4*)&As[0][m][a_kc] = v0;
            *(f16x4*)&As[1][m][a_kc] = v1;
            *(f16x4*)&As[2][m][a_kc] = v2;
        }
        // ---- stage B ({0,1} activations), f32->f16 + transpose ----
        {
            float4 r0 = *(const float4*)&Bp[(long)(k0 + b_kq * 4 + 0) * N + n0 + b_nq * 4];
            float4 r1 = *(const float4*)&Bp[(long)(k0 + b_kq * 4 + 1) * N + n0 + b_nq * 4];
            float4 r2 = *(const float4*)&Bp[(long)(k0 + b_kq * 4 + 2) * N + n0 + b_nq * 4];
            float4 r3 = *(const float4*)&Bp[(long)(k0 + b_kq * 4 + 3) * N + n0 + b_nq * 4];
            f16x4 p;
            p = (f16x4){(_Float16)r0.x, (_Float16)r1.x, (_Float16)r2.x, (_Float16)r3.x};
            *(f16x4*)&Bs[b_nq * 4 + 0][b_kq * 4] = p;
            p = (f16x4){(_Float16)r0.y, (_Float16)r1.y, (_Float16)r2.y, (_Float16)r3.y};
            *(f16x4*)&Bs[b_nq * 4 + 1][b_kq * 4] = p;
            p = (f16x4){(_Float16)r0.z, (_Float16)r1.z, (_Float16)r2.z, (_Float16)r3.z};
            *(f16x4*)&Bs[b_nq * 4 + 2][b_kq * 4] = p;
            p = (f16x4){(_Float16)r0.w, (_Float16)r1.w, (_Float16)r2.w, (_Float16)r3.w};
            *(f16x4*)&Bs[b_nq * 4 + 3][b_kq * 4] = p;
        }
        __syncthreads();

        // ---- fragments + MFMA ----
        f16x8 bf[4];
#pragma unroll
        for (int j = 0; j < 4; j++)
            bf[j] = *(const f16x8*)&Bs[wcol + j * 16 + lm][lq * 8];

#pragma unroll
        for (int p = 0; p < 3; p++) {
            f16x8 af[4];
#pragma unroll
            for (int i = 0; i < 4; i++)
                af[i] = *(const f16x8*)&As[p][wrow + i * 16 + lm][lq * 8];
#pragma unroll
            for (int i = 0; i < 4; i++)
#pragma unroll
                for (int j = 0; j < 4; j++)
                    acc[p][i][j] = __builtin_amdgcn_mfma_f32_16x16x32_f16(
                        af[i], bf[j], acc[p][i][j], 0, 0, 0);
        }
        __syncthreads();
    }

    // ---- epilogue: combine planes in f64 (exact), add bias, store f32 ----
#pragma unroll
    for (int i = 0; i < 4; i++) {
#pragma unroll
        for (int r = 0; r < 4; r++) {
            const int row = m0 + wrow + i * 16 + lq * 4 + r;
            const double bv = (double)bias[row];
#pragma unroll
            for (int j = 0; j < 4; j++) {
                double s = (double)acc[0][i][j][r]
                         + (double)acc[1][i][j][r] * 4.8828125e-4      // 2^-11
                         + (double)acc[2][i][j][r] * 4.76837158203125e-7 // 2^-21
                         + bv;
                Cp[(long)row * N + n0 + wcol + j * 16 + lm] = (float)s;
            }
        }
    }
}

// In-place CUBA-LIF scan: rows of (row, T) currents -> binary spikes.
// Voltage recurrence in double (matches f64 numpy reference).
__global__ __launch_bounds__(256) void lif_kernel(float* __restrict__ data,
                                                  long nrows, int T)
{
    long r = (long)blockIdx.x * blockDim.x + threadIdx.x;
    if (r >= nrows) return;
    float* p = data + r * (long)T;
    double v = 0.0;
    for (int t = 0; t < T; t += 4) {
        float4 c = *(float4*)(p + t);
        float4 s;
        v = 0.95 * v + (double)c.x;
        s.x = (v >= 1.0) ? 1.f : 0.f; if (v >= 1.0) v = 0.0;
        v = 0.95 * v + (double)c.y;
        s.y = (v >= 1.0) ? 1.f : 0.f; if (v >= 1.0) v = 0.0;
        v = 0.95 * v + (double)c.z;
        s.z = (v >= 1.0) ? 1.f : 0.f; if (v >= 1.0) v = 0.0;
        v = 0.95 * v + (double)c.w;
        s.w = (v >= 1.0) ? 1.f : 0.f; if (v >= 1.0) v = 0.0;
        *(float4*)(p + t) = s;
    }
}

extern "C" void kernel_launch(void* const* d_in, const int* in_sizes, int n_in,
                              void* d_out, int out_size, void* d_ws, size_t ws_size,
                              hipStream_t stream)
{
    const float* x  = (const float*)d_in[0];  // (32, 512, 1024)
    const float* w1 = (const float*)d_in[1];  // (2048, 512)
    const float* b1 = (const float*)d_in[2];  // (2048)
    const float* w2 = (const float*)d_in[3];  // (256, 2048)
    const float* b2 = (const float*)d_in[4];  // (256)

    float* out  = (float*)d_out;
    float* spk1 = out;                              // (32, 2048, 1024)
    float* spk2 = out + (long)32 * 2048 * 1024;     // (32, 256, 1024)

    // layer 1: cur1 = w1 @ x[b] + b1  (M=2048, N=1024, K=512)
    {
        dim3 grid(1024 / 128, 2048 / 128, 32);
        gemm_f16x3_kernel<<<grid, 256, 0, stream>>>(
            w1, x, b1, spk1, 2048, 1024, 512,
            (long)512 * 1024, (long)2048 * 1024);
    }
    lif_kernel<<<(65536 + 255) / 256, 256, 0, stream>>>(spk1, 65536, 1024);

    // layer 2: cur2 = w2 @ spk1[b] + b2  (M=256, N=1024, K=2048)
    {
        dim3 grid(1024 / 128, 256 / 128, 32);
        gemm_f16x3_kernel<<<grid, 256, 0, stream>>>(
            w2, spk1, b2, spk2, 256, 1024, 2048,
            (long)2048 * 1024, (long)256 * 1024);
    }
    lif_kernel<<<(8192 + 255) / 256, 256, 0, stream>>>(spk2, 8192, 1024);
}

// Round 4
// 942.553 us; speedup vs baseline: 2.6606x; 1.5877x over previous
//
#include <hip/hip_runtime.h>

// ---------------------------------------------------------------------------
// LavaNetwork, bit-exact 3-plane f16 MFMA GEMM (numerics identical to the
// passing round-3 kernel), restructured for throughput:
//  - weight planes precomputed once per launch into d_ws, tiled [k/32][p][m][32]
//  - activations pre-binarized to i8, transposed [b][t][k]
//  - GEMM: BK=64, unpadded 64B LDS rows, A via global_load_lds dwordx4,
//    B via i8 -> f16 bit-trick (activations are {0,1})
//  - LIF: LDS-chunked coalesced scan; LIF1 also emits transposed i8 spikes
//    for GEMM2's B operand.
// Fallback to the proven round-3 path if ws_size is too small.
// ---------------------------------------------------------------------------

typedef _Float16 f16x8 __attribute__((ext_vector_type(8)));
typedef _Float16 f16x4 __attribute__((ext_vector_type(4)));
typedef float f32x4 __attribute__((ext_vector_type(4)));

// Exact 3-plane split (proven in round 3): w = q0 + q1*2^-11 + q2*2^-21 with
// each stored plane an exact-in-f16 integer-times-power-of-2.
__device__ inline void split3(float w, _Float16& q0, _Float16& q1, _Float16& q2) {
    float p0 = rintf(w * 4096.f) * 2.44140625e-4f;
    float r1 = w - p0;
    float p1s = rintf(r1 * 8388608.f) * 2.44140625e-4f;
    float r2 = r1 - p1s * 4.8828125e-4f;
    float p2s = rintf(r2 * 1.7179869184e10f) * 1.220703125e-4f;
    q0 = (_Float16)p0;
    q1 = (_Float16)p1s;
    q2 = (_Float16)p2s;
}

#define GLDS(g, l) __builtin_amdgcn_global_load_lds( \
    (const __attribute__((address_space(1))) void*)(g), \
    (__attribute__((address_space(3))) void*)(l), 16, 0, 0)

// ======================= fast path =======================

// w (M,K) f32 -> wp [K/32][3][M][32] f16 planes
__global__ __launch_bounds__(256) void prep_w(const float* __restrict__ A,
                                              _Float16* __restrict__ wp,
                                              int M, int K)
{
    long gtid = (long)blockIdx.x * 256 + threadIdx.x;
    int K8 = K / 8;
    int m = (int)(gtid / K8), rem = (int)(gtid % K8);
    int kt = rem >> 2, c = rem & 3;
    const float* src = A + (long)m * K + kt * 32 + c * 8;
    float4 wa = *(const float4*)src;
    float4 wb = *(const float4*)(src + 4);
    float wv[8] = {wa.x, wa.y, wa.z, wa.w, wb.x, wb.y, wb.z, wb.w};
    f16x8 v0, v1, v2;
#pragma unroll
    for (int j = 0; j < 8; j++) {
        _Float16 a, b, cq;
        split3(wv[j], a, b, cq);
        v0[j] = a; v1[j] = b; v2[j] = cq;
    }
    long base = (((long)kt * 3) * M + m) * 32 + c * 8;
    *(f16x8*)&wp[base] = v0;
    *(f16x8*)&wp[base + (long)M * 32] = v1;
    *(f16x8*)&wp[base + 2L * M * 32] = v2;
}

// x [b][512][1024] f32 -> x8t [b][1024][512] i8 (transpose + binarize)
__global__ __launch_bounds__(256) void prep_x(const float* __restrict__ x,
                                              unsigned char* __restrict__ xt)
{
    __shared__ float xs[64][68];
    const int b = blockIdx.z, i0 = blockIdx.y * 64, t0 = blockIdx.x * 64;
    const float* xb = x + ((long)b * 512 + i0) * 1024 + t0;
#pragma unroll
    for (int p = 0; p < 4; p++) {
        int f = threadIdx.x + p * 256;        // 0..1023
        int i = f >> 4, t4 = (f & 15) * 4;
        *(float4*)&xs[i][t4] = *(const float4*)&xb[(long)i * 1024 + t4];
    }
    __syncthreads();
    int tt = threadIdx.x >> 2, c = threadIdx.x & 3;
    unsigned char bytes[16];
#pragma unroll
    for (int j = 0; j < 16; j++)
        bytes[j] = (unsigned char)xs[c * 16 + j][tt];
    *(uint4*)&xt[((long)b * 1024 + t0 + tt) * 512 + i0 + c * 16] = *(uint4*)bytes;
}

// GEMM: C[b][M][1024] = combine3(planes @ act) + bias
// wp: [K/32][3][M][32] f16; bx: [b][1024][K] i8 ({0,1})
__global__ __launch_bounds__(256, 2) void gemm_planes(
    const _Float16* __restrict__ wp,
    const unsigned char* __restrict__ bx,
    const float* __restrict__ bias,
    float* __restrict__ C,
    int M, int K)
{
    __shared__ _Float16 As[2][3][128][32];   // 49152 B
    __shared__ _Float16 Bs[2][128][32];      // 16384 B

    const int b = blockIdx.z;
    const unsigned char* bxb = bx + (long)b * 1024 * K;
    float* Cp = C + (long)b * M * 1024;
    const int m0 = blockIdx.y * 128, n0 = blockIdx.x * 128;
    const int tid = threadIdx.x, lane = tid & 63, wave = tid >> 6;
    const int wrow = (wave >> 1) * 64, wcol = (wave & 1) * 64;
    const int lm = lane & 15, lq = lane >> 4;
    const int bn = tid >> 1, bh = tid & 1;   // B staging: row, half

    f32x4 acc[3][4][4];
#pragma unroll
    for (int p = 0; p < 3; p++)
#pragma unroll
        for (int i = 0; i < 4; i++)
#pragma unroll
            for (int j = 0; j < 4; j++) acc[p][i][j] = (f32x4)0.f;

    const int niter = K >> 6;
    for (int kt2 = 0; kt2 < niter; kt2++) {
        // ---- A: 48 slabs x 1024B via global_load_lds (lane-contiguous) ----
        for (int r = wave; r < 48; r += 4) {
            int sub = r / 24, rp = r % 24, p = rp >> 3, slab = rp & 7;
            int kt = kt2 * 2 + sub;
            const _Float16* g = wp + (((long)kt * 3 + p) * M + m0 + slab * 16) * 32
                                + lane * 8;
            GLDS(g, &As[sub][p][slab * 16][0]);
        }
        // ---- B: i8 -> f16 bit-trick ({0,1} values) ----
#pragma unroll
        for (int sub = 0; sub < 2; sub++) {
            int kt = kt2 * 2 + sub;
            uint4 w = *(const uint4*)&bxb[((long)(n0 + bn)) * K + kt * 32 + bh * 16];
            unsigned ww[4] = {w.x, w.y, w.z, w.w};
            unsigned out[8];
#pragma unroll
            for (int u = 0; u < 4; u++) {
                out[u * 2 + 0] = ((ww[u] & 1u) | ((ww[u] & 0x100u) << 8)) * 0x3C00u;
                out[u * 2 + 1] = (((ww[u] >> 16) & 1u) | ((ww[u] & 0x1000000u) >> 8)) * 0x3C00u;
            }
            *(uint4*)&Bs[sub][bn][bh * 16] = *(uint4*)&out[0];
            *(uint4*)&Bs[sub][bn][bh * 16 + 8] = *(uint4*)&out[4];
        }
        __syncthreads();

#pragma unroll
        for (int sub = 0; sub < 2; sub++) {
            f16x8 bf[4];
#pragma unroll
            for (int j = 0; j < 4; j++)
                bf[j] = *(const f16x8*)&Bs[sub][wcol + j * 16 + lm][lq * 8];
#pragma unroll
            for (int p = 0; p < 3; p++) {
                f16x8 af[4];
#pragma unroll
                for (int i = 0; i < 4; i++)
                    af[i] = *(const f16x8*)&As[sub][p][wrow + i * 16 + lm][lq * 8];
#pragma unroll
                for (int i = 0; i < 4; i++)
#pragma unroll
                    for (int j = 0; j < 4; j++)
                        acc[p][i][j] = __builtin_amdgcn_mfma_f32_16x16x32_f16(
                            af[i], bf[j], acc[p][i][j], 0, 0, 0);
            }
        }
        __syncthreads();
    }

    // ---- epilogue: exact f64 combine + bias ----
#pragma unroll
    for (int i = 0; i < 4; i++) {
#pragma unroll
        for (int r = 0; r < 4; r++) {
            const int row = m0 + wrow + i * 16 + lq * 4 + r;
            const double bv = (double)bias[row];
#pragma unroll
            for (int j = 0; j < 4; j++) {
                double s = (double)acc[0][i][j][r]
                         + (double)acc[1][i][j][r] * 4.8828125e-4
                         + (double)acc[2][i][j][r] * 4.76837158203125e-7
                         + bv;
                Cp[(long)row * 1024 + n0 + wcol + j * 16 + lm] = (float)s;
            }
        }
    }
}

// LDS-chunked coalesced LIF. cur rows (flat) of length 1024, in-place spikes.
// EMIT: also write i8 spikes transposed [b][t][2048] (requires RPB|2048 rows
// within one batch).
template <int RPB, bool EMIT>
__global__ __launch_bounds__(256) void lif_lds(float* __restrict__ cur,
                                               unsigned char* __restrict__ spk8)
{
    __shared__ float cs[RPB][36];
    const long rowbase = (long)blockIdx.x * RPB;
    float* base = cur + rowbase * 1024;
    const int tid = threadIdx.x;
    const int b = (int)(rowbase >> 11);
    const int m0 = (int)(rowbase & 2047);
    unsigned char* sb = EMIT ? spk8 + (long)b * 1024 * 2048 + m0 : nullptr;
    double v = 0.0;
    const int NV = RPB * 32 / 4;
    for (int tc = 0; tc < 1024; tc += 32) {
        for (int f = tid; f < NV; f += 256) {
            int row = f >> 3, t4 = (f & 7) * 4;
            *(float4*)&cs[row][t4] = *(const float4*)&base[(long)row * 1024 + tc + t4];
        }
        __syncthreads();
        if (tid < RPB) {
#pragma unroll
            for (int j = 0; j < 32; j++) {
                v = 0.95 * v + (double)cs[tid][j];
                bool s = v >= 1.0;
                cs[tid][j] = s ? 1.f : 0.f;
                if (s) v = 0.0;
            }
        }
        __syncthreads();
        for (int f = tid; f < NV; f += 256) {
            int row = f >> 3, t4 = (f & 7) * 4;
            *(float4*)&base[(long)row * 1024 + tc + t4] = *(float4*)&cs[row][t4];
        }
        if (EMIT) {
            const int NQ = 32 * (RPB / 4);
            for (int q = tid; q < NQ; q += 256) {
                int t = q >> (__builtin_ctz(RPB / 4)), mq = q & (RPB / 4 - 1);
                uchar4 u;
                u.x = (unsigned char)cs[mq * 4 + 0][t];
                u.y = (unsigned char)cs[mq * 4 + 1][t];
                u.z = (unsigned char)cs[mq * 4 + 2][t];
                u.w = (unsigned char)cs[mq * 4 + 3][t];
                *(uchar4*)&sb[(long)(tc + t) * 2048 + mq * 4] = u;
            }
        }
        __syncthreads();
    }
}

// ======================= fallback path (round 3, proven) =======================

__global__ __launch_bounds__(256) void gemm_f16x3_kernel(
    const float* __restrict__ A, const float* __restrict__ Bmat,
    const float* __restrict__ bias, float* __restrict__ C,
    int M, int N, int K, long sB, long sC)
{
    __shared__ _Float16 As[3][128][40];
    __shared__ _Float16 Bsh[128][40];
    const int batch = blockIdx.z;
    const float* Bp = Bmat + (long)batch * sB;
    float* Cp = C + (long)batch * sC;
    const int m0 = blockIdx.y * 128, n0 = blockIdx.x * 128;
    const int tid = threadIdx.x, lane = tid & 63, wave = tid >> 6;
    const int wrow = (wave >> 1) * 64, wcol = (wave & 1) * 64;
    const int lm = lane & 15, lq = lane >> 4;
    const int a_mo = tid >> 3, a_kc = (tid & 7) * 4;
    const int b_kq = tid >> 5, b_nq = tid & 31;

    f32x4 acc[3][4][4];
#pragma unroll
    for (int p = 0; p < 3; p++)
#pragma unroll
        for (int i = 0; i < 4; i++)
#pragma unroll
            for (int j = 0; j < 4; j++) acc[p][i][j] = (f32x4)0.f;

    for (int k0 = 0; k0 < K; k0 += 32) {
#pragma unroll
        for (int i = 0; i < 4; i++) {
            const int m = i * 32 + a_mo;
            float4 w = *(const float4*)&A[(long)(m0 + m) * K + k0 + a_kc];
            _Float16 a0[4], a1[4], a2[4];
            split3(w.x, a0[0], a1[0], a2[0]);
            split3(w.y, a0[1], a1[1], a2[1]);
            split3(w.z, a0[2], a1[2], a2[2]);
            split3(w.w, a0[3], a1[3], a2[3]);
            *(f16x4*)&As[0][m][a_kc] = (f16x4){a0[0], a0[1], a0[2], a0[3]};
            *(f16x4*)&As[1][m][a_kc] = (f16x4){a1[0], a1[1], a1[2], a1[3]};
            *(f16x4*)&As[2][m][a_kc] = (f16x4){a2[0], a2[1], a2[2], a2[3]};
        }
        {
            float4 r0 = *(const float4*)&Bp[(long)(k0 + b_kq * 4 + 0) * N + n0 + b_nq * 4];
            float4 r1 = *(const float4*)&Bp[(long)(k0 + b_kq * 4 + 1) * N + n0 + b_nq * 4];
            float4 r2 = *(const float4*)&Bp[(long)(k0 + b_kq * 4 + 2) * N + n0 + b_nq * 4];
            float4 r3 = *(const float4*)&Bp[(long)(k0 + b_kq * 4 + 3) * N + n0 + b_nq * 4];
            *(f16x4*)&Bsh[b_nq * 4 + 0][b_kq * 4] =
                (f16x4){(_Float16)r0.x, (_Float16)r1.x, (_Float16)r2.x, (_Float16)r3.x};
            *(f16x4*)&Bsh[b_nq * 4 + 1][b_kq * 4] =
                (f16x4){(_Float16)r0.y, (_Float16)r1.y, (_Float16)r2.y, (_Float16)r3.y};
            *(f16x4*)&Bsh[b_nq * 4 + 2][b_kq * 4] =
                (f16x4){(_Float16)r0.z, (_Float16)r1.z, (_Float16)r2.z, (_Float16)r3.z};
            *(f16x4*)&Bsh[b_nq * 4 + 3][b_kq * 4] =
                (f16x4){(_Float16)r0.w, (_Float16)r1.w, (_Float16)r2.w, (_Float16)r3.w};
        }
        __syncthreads();
        f16x8 bf[4];
#pragma unroll
        for (int j = 0; j < 4; j++)
            bf[j] = *(const f16x8*)&Bsh[wcol + j * 16 + lm][lq * 8];
#pragma unroll
        for (int p = 0; p < 3; p++) {
            f16x8 af[4];
#pragma unroll
            for (int i = 0; i < 4; i++)
                af[i] = *(const f16x8*)&As[p][wrow + i * 16 + lm][lq * 8];
#pragma unroll
            for (int i = 0; i < 4; i++)
#pragma unroll
                for (int j = 0; j < 4; j++)
                    acc[p][i][j] = __builtin_amdgcn_mfma_f32_16x16x32_f16(
                        af[i], bf[j], acc[p][i][j], 0, 0, 0);
        }
        __syncthreads();
    }
#pragma unroll
    for (int i = 0; i < 4; i++) {
#pragma unroll
        for (int r = 0; r < 4; r++) {
            const int row = m0 + wrow + i * 16 + lq * 4 + r;
            const double bv = (double)bias[row];
#pragma unroll
            for (int j = 0; j < 4; j++) {
                double s = (double)acc[0][i][j][r]
                         + (double)acc[1][i][j][r] * 4.8828125e-4
                         + (double)acc[2][i][j][r] * 4.76837158203125e-7 + bv;
                Cp[(long)row * N + n0 + wcol + j * 16 + lm] = (float)s;
            }
        }
    }
}

__global__ __launch_bounds__(256) void lif_rows(float* __restrict__ data,
                                                long nrows, int T)
{
    long r = (long)blockIdx.x * blockDim.x + threadIdx.x;
    if (r >= nrows) return;
    float* p = data + r * (long)T;
    double v = 0.0;
    for (int t = 0; t < T; t += 4) {
        float4 c = *(float4*)(p + t);
        float4 s;
        v = 0.95 * v + (double)c.x; s.x = (v >= 1.0) ? 1.f : 0.f; if (v >= 1.0) v = 0.0;
        v = 0.95 * v + (double)c.y; s.y = (v >= 1.0) ? 1.f : 0.f; if (v >= 1.0) v = 0.0;
        v = 0.95 * v + (double)c.z; s.z = (v >= 1.0) ? 1.f : 0.f; if (v >= 1.0) v = 0.0;
        v = 0.95 * v + (double)c.w; s.w = (v >= 1.0) ? 1.f : 0.f; if (v >= 1.0) v = 0.0;
        *(float4*)(p + t) = s;
    }
}

// ======================= launch =======================

extern "C" void kernel_launch(void* const* d_in, const int* in_sizes, int n_in,
                              void* d_out, int out_size, void* d_ws, size_t ws_size,
                              hipStream_t stream)
{
    const float* x  = (const float*)d_in[0];  // (32, 512, 1024)
    const float* w1 = (const float*)d_in[1];  // (2048, 512)
    const float* b1 = (const float*)d_in[2];  // (2048)
    const float* w2 = (const float*)d_in[3];  // (256, 2048)
    const float* b2 = (const float*)d_in[4];  // (256)

    float* out  = (float*)d_out;
    float* spk1 = out;                              // (32, 2048, 1024)
    float* spk2 = out + (long)32 * 2048 * 1024;     // (32, 256, 1024)

    // ws layout
    const size_t WP1 = 6291456;        // [16][3][2048][32] f16
    const size_t WP2 = 3145728;        // [64][3][256][32] f16
    const size_t X8T = 16777216;       // [32][1024][512] i8
    const size_t SPK = 67108864;       // [32][1024][2048] i8
    const size_t NEED = WP1 + WP2 + X8T + SPK;

    if (ws_size >= NEED) {
        char* ws = (char*)d_ws;
        _Float16* wp1 = (_Float16*)ws;
        _Float16* wp2 = (_Float16*)(ws + WP1);
        unsigned char* x8t = (unsigned char*)(ws + WP1 + WP2);
        unsigned char* spk8 = (unsigned char*)(ws + WP1 + WP2 + X8T);

        prep_w<<<512, 256, 0, stream>>>(w1, wp1, 2048, 512);
        prep_w<<<256, 256, 0, stream>>>(w2, wp2, 256, 2048);
        prep_x<<<dim3(16, 8, 32), 256, 0, stream>>>(x, x8t);

        gemm_planes<<<dim3(8, 16, 32), 256, 0, stream>>>(wp1, x8t, b1, spk1, 2048, 512);
        lif_lds<256, true><<<256, 256, 0, stream>>>(spk1, spk8);
        gemm_planes<<<dim3(8, 2, 32), 256, 0, stream>>>(wp2, spk8, b2, spk2, 256, 2048);
        lif_lds<128, false><<<64, 256, 0, stream>>>(spk2, nullptr);
    } else {
        // round-3 fallback (proven)
        gemm_f16x3_kernel<<<dim3(8, 16, 32), 256, 0, stream>>>(
            w1, x, b1, spk1, 2048, 1024, 512, (long)512 * 1024, (long)2048 * 1024);
        lif_rows<<<(65536 + 255) / 256, 256, 0, stream>>>(spk1, 65536, 1024);
        gemm_f16x3_kernel<<<dim3(8, 2, 32), 256, 0, stream>>>(
            w2, spk1, b2, spk2, 256, 1024, 2048, (long)2048 * 1024, (long)256 * 1024);
        lif_rows<<<(8192 + 255) / 256, 256, 0, stream>>>(spk2, 8192, 1024);
    }
}

// Round 5
// 921.285 us; speedup vs baseline: 2.7220x; 1.0231x over previous
//
#include <hip/hip_runtime.h>

// ---------------------------------------------------------------------------
// LavaNetwork, bit-exact 3-plane f16 MFMA GEMM.
// Round-5 structure:
//  - GEMM1 emits cur1 TRANSPOSED [b][t][m] (operand-swap, free) into spk1 region
//  - lif1_t: thread-per-row coalesced scan, no LDS/barriers; emits i8 spikes
//    [b][t][m] for GEMM2 + 1024-bit masks
//  - expand_spk: masks -> f32 spikes [b][m][t] (overwrites dead cur1t)
//  - GEMM2 + lif_lds<128> unchanged (proven round 4)
// Fallback tiers if ws too small.
// ---------------------------------------------------------------------------

typedef _Float16 f16x8 __attribute__((ext_vector_type(8)));
typedef _Float16 f16x4 __attribute__((ext_vector_type(4)));
typedef float f32x4 __attribute__((ext_vector_type(4)));

__device__ inline void split3(float w, _Float16& q0, _Float16& q1, _Float16& q2) {
    float p0 = rintf(w * 4096.f) * 2.44140625e-4f;
    float r1 = w - p0;
    float p1s = rintf(r1 * 8388608.f) * 2.44140625e-4f;
    float r2 = r1 - p1s * 4.8828125e-4f;
    float p2s = rintf(r2 * 1.7179869184e10f) * 1.220703125e-4f;
    q0 = (_Float16)p0;
    q1 = (_Float16)p1s;
    q2 = (_Float16)p2s;
}

#define GLDS(g, l) __builtin_amdgcn_global_load_lds( \
    (const __attribute__((address_space(1))) void*)(g), \
    (__attribute__((address_space(3))) void*)(l), 16, 0, 0)

// ======================= prep =======================

// w (M,K) f32 -> wp [K/32][3][M][32] f16 planes
__global__ __launch_bounds__(256) void prep_w(const float* __restrict__ A,
                                              _Float16* __restrict__ wp,
                                              int M, int K)
{
    long gtid = (long)blockIdx.x * 256 + threadIdx.x;
    int K8 = K / 8;
    int m = (int)(gtid / K8), rem = (int)(gtid % K8);
    int kt = rem >> 2, c = rem & 3;
    const float* src = A + (long)m * K + kt * 32 + c * 8;
    float4 wa = *(const float4*)src;
    float4 wb = *(const float4*)(src + 4);
    float wv[8] = {wa.x, wa.y, wa.z, wa.w, wb.x, wb.y, wb.z, wb.w};
    f16x8 v0, v1, v2;
#pragma unroll
    for (int j = 0; j < 8; j++) {
        _Float16 a, b, cq;
        split3(wv[j], a, b, cq);
        v0[j] = a; v1[j] = b; v2[j] = cq;
    }
    long base = (((long)kt * 3) * M + m) * 32 + c * 8;
    *(f16x8*)&wp[base] = v0;
    *(f16x8*)&wp[base + (long)M * 32] = v1;
    *(f16x8*)&wp[base + 2L * M * 32] = v2;
}

// x [b][512][1024] f32 -> x8t [b][1024][512] i8 (transpose + binarize)
__global__ __launch_bounds__(256) void prep_x(const float* __restrict__ x,
                                              unsigned char* __restrict__ xt)
{
    __shared__ float xs[64][68];
    const int b = blockIdx.z, i0 = blockIdx.y * 64, t0 = blockIdx.x * 64;
    const float* xb = x + ((long)b * 512 + i0) * 1024 + t0;
#pragma unroll
    for (int p = 0; p < 4; p++) {
        int f = threadIdx.x + p * 256;
        int i = f >> 4, t4 = (f & 15) * 4;
        *(float4*)&xs[i][t4] = *(const float4*)&xb[(long)i * 1024 + t4];
    }
    __syncthreads();
    int tt = threadIdx.x >> 2, c = threadIdx.x & 3;
    unsigned char bytes[16];
#pragma unroll
    for (int j = 0; j < 16; j++)
        bytes[j] = (unsigned char)xs[c * 16 + j][tt];
    *(uint4*)&xt[((long)b * 1024 + t0 + tt) * 512 + i0 + c * 16] = *(uint4*)bytes;
}

// ======================= GEMMs =======================

// C[b][M][1024] = combine3(W @ act) + bias    (row = m, col = t)  [round-4]
__global__ __launch_bounds__(256, 2) void gemm_planes(
    const _Float16* __restrict__ wp,
    const unsigned char* __restrict__ bx,
    const float* __restrict__ bias,
    float* __restrict__ C,
    int M, int K)
{
    __shared__ _Float16 As[2][3][128][32];
    __shared__ _Float16 Bs[2][128][32];

    const int b = blockIdx.z;
    const unsigned char* bxb = bx + (long)b * 1024 * K;
    float* Cp = C + (long)b * M * 1024;
    const int m0 = blockIdx.y * 128, n0 = blockIdx.x * 128;
    const int tid = threadIdx.x, lane = tid & 63, wave = tid >> 6;
    const int wrow = (wave >> 1) * 64, wcol = (wave & 1) * 64;
    const int lm = lane & 15, lq = lane >> 4;
    const int bn = tid >> 1, bh = tid & 1;

    f32x4 acc[3][4][4];
#pragma unroll
    for (int p = 0; p < 3; p++)
#pragma unroll
        for (int i = 0; i < 4; i++)
#pragma unroll
            for (int j = 0; j < 4; j++) acc[p][i][j] = (f32x4)0.f;

    const int niter = K >> 6;
    for (int kt2 = 0; kt2 < niter; kt2++) {
        for (int r = wave; r < 48; r += 4) {
            int sub = r / 24, rp = r % 24, p = rp >> 3, slab = rp & 7;
            int kt = kt2 * 2 + sub;
            const _Float16* g = wp + (((long)kt * 3 + p) * M + m0 + slab * 16) * 32
                                + lane * 8;
            GLDS(g, &As[sub][p][slab * 16][0]);
        }
#pragma unroll
        for (int sub = 0; sub < 2; sub++) {
            int kt = kt2 * 2 + sub;
            uint4 w = *(const uint4*)&bxb[((long)(n0 + bn)) * K + kt * 32 + bh * 16];
            unsigned ww[4] = {w.x, w.y, w.z, w.w};
            unsigned out[8];
#pragma unroll
            for (int u = 0; u < 4; u++) {
                out[u * 2 + 0] = ((ww[u] & 1u) | ((ww[u] & 0x100u) << 8)) * 0x3C00u;
                out[u * 2 + 1] = (((ww[u] >> 16) & 1u) | ((ww[u] & 0x1000000u) >> 8)) * 0x3C00u;
            }
            *(uint4*)&Bs[sub][bn][bh * 16] = *(uint4*)&out[0];
            *(uint4*)&Bs[sub][bn][bh * 16 + 8] = *(uint4*)&out[4];
        }
        __syncthreads();

#pragma unroll
        for (int sub = 0; sub < 2; sub++) {
            f16x8 bf[4];
#pragma unroll
            for (int j = 0; j < 4; j++)
                bf[j] = *(const f16x8*)&Bs[sub][wcol + j * 16 + lm][lq * 8];
#pragma unroll
            for (int p = 0; p < 3; p++) {
                f16x8 af[4];
#pragma unroll
                for (int i = 0; i < 4; i++)
                    af[i] = *(const f16x8*)&As[sub][p][wrow + i * 16 + lm][lq * 8];
#pragma unroll
                for (int i = 0; i < 4; i++)
#pragma unroll
                    for (int j = 0; j < 4; j++)
                        acc[p][i][j] = __builtin_amdgcn_mfma_f32_16x16x32_f16(
                            af[i], bf[j], acc[p][i][j], 0, 0, 0);
            }
        }
        __syncthreads();
    }

#pragma unroll
    for (int i = 0; i < 4; i++) {
#pragma unroll
        for (int r = 0; r < 4; r++) {
            const int row = m0 + wrow + i * 16 + lq * 4 + r;
            const double bv = (double)bias[row];
#pragma unroll
            for (int j = 0; j < 4; j++) {
                double s = (double)acc[0][i][j][r]
                         + (double)acc[1][i][j][r] * 4.8828125e-4
                         + (double)acc[2][i][j][r] * 4.76837158203125e-7
                         + bv;
                Cp[(long)row * 1024 + n0 + wcol + j * 16 + lm] = (float)s;
            }
        }
    }
}

// Transposed variant: Ct[b][t][M] = combine3(act @ W^T) + bias[m]
// (activations as A operand, weights as B operand; D row = t, col = m)
__global__ __launch_bounds__(256, 2) void gemm_planes_T(
    const _Float16* __restrict__ wp,
    const unsigned char* __restrict__ bx,
    const float* __restrict__ bias,
    float* __restrict__ Ct,
    int M, int K)
{
    __shared__ _Float16 As[2][3][128][32];   // weights [m][k]
    __shared__ _Float16 Bs[2][128][32];      // acts    [t][k]

    const int b = blockIdx.z;
    const unsigned char* bxb = bx + (long)b * 1024 * K;
    float* Cp = Ct + (long)b * 1024 * M;
    const int m0 = blockIdx.x * 128, t0 = blockIdx.y * 128;
    const int tid = threadIdx.x, lane = tid & 63, wave = tid >> 6;
    const int wt = (wave >> 1) * 64, wm = (wave & 1) * 64;
    const int lm = lane & 15, lq = lane >> 4;
    const int bn = tid >> 1, bh = tid & 1;

    f32x4 acc[3][4][4];   // [plane][t-sub][m-sub]
#pragma unroll
    for (int p = 0; p < 3; p++)
#pragma unroll
        for (int i = 0; i < 4; i++)
#pragma unroll
            for (int j = 0; j < 4; j++) acc[p][i][j] = (f32x4)0.f;

    const int niter = K >> 6;
    for (int kt2 = 0; kt2 < niter; kt2++) {
        for (int r = wave; r < 48; r += 4) {
            int sub = r / 24, rp = r % 24, p = rp >> 3, slab = rp & 7;
            int kt = kt2 * 2 + sub;
            const _Float16* g = wp + (((long)kt * 3 + p) * M + m0 + slab * 16) * 32
                                + lane * 8;
            GLDS(g, &As[sub][p][slab * 16][0]);
        }
#pragma unroll
        for (int sub = 0; sub < 2; sub++) {
            int kt = kt2 * 2 + sub;
            uint4 w = *(const uint4*)&bxb[((long)(t0 + bn)) * K + kt * 32 + bh * 16];
            unsigned ww[4] = {w.x, w.y, w.z, w.w};
            unsigned out[8];
#pragma unroll
            for (int u = 0; u < 4; u++) {
                out[u * 2 + 0] = ((ww[u] & 1u) | ((ww[u] & 0x100u) << 8)) * 0x3C00u;
                out[u * 2 + 1] = (((ww[u] >> 16) & 1u) | ((ww[u] & 0x1000000u) >> 8)) * 0x3C00u;
            }
            *(uint4*)&Bs[sub][bn][bh * 16] = *(uint4*)&out[0];
            *(uint4*)&Bs[sub][bn][bh * 16 + 8] = *(uint4*)&out[4];
        }
        __syncthreads();

#pragma unroll
        for (int sub = 0; sub < 2; sub++) {
            f16x8 af[4];   // activation frags (A operand, t rows)
#pragma unroll
            for (int i = 0; i < 4; i++)
                af[i] = *(const f16x8*)&Bs[sub][wt + i * 16 + lm][lq * 8];
#pragma unroll
            for (int p = 0; p < 3; p++) {
                f16x8 wf[4];   // weight frags (B operand, m cols)
#pragma unroll
                for (int j = 0; j < 4; j++)
                    wf[j] = *(const f16x8*)&As[sub][p][wm + j * 16 + lm][lq * 8];
#pragma unroll
                for (int i = 0; i < 4; i++)
#pragma unroll
                    for (int j = 0; j < 4; j++)
                        acc[p][i][j] = __builtin_amdgcn_mfma_f32_16x16x32_f16(
                            af[i], wf[j], acc[p][i][j], 0, 0, 0);
            }
        }
        __syncthreads();
    }

    // bias per m-column (lane gather, consecutive lm -> consecutive addrs)
    double bvj[4];
#pragma unroll
    for (int j = 0; j < 4; j++) bvj[j] = (double)bias[m0 + wm + j * 16 + lm];

#pragma unroll
    for (int i = 0; i < 4; i++) {
#pragma unroll
        for (int r = 0; r < 4; r++) {
            const int trow = t0 + wt + i * 16 + lq * 4 + r;
#pragma unroll
            for (int j = 0; j < 4; j++) {
                double s = (double)acc[0][i][j][r]
                         + (double)acc[1][i][j][r] * 4.8828125e-4
                         + (double)acc[2][i][j][r] * 4.76837158203125e-7
                         + bvj[j];
                Cp[(long)trow * M + m0 + wm + j * 16 + lm] = (float)s;
            }
        }
    }
}

// ======================= LIF =======================

// Coalesced thread-per-row scan over transposed cur [b][1024][2048].
// Emits i8 spikes [b][t][2048] and per-row 1024-bit masks [b][32 words][2048].
__global__ __launch_bounds__(1024) void lif1_t(
    const float* __restrict__ ct,
    unsigned char* __restrict__ spk8,
    unsigned* __restrict__ mask_ws)
{
    const int b = blockIdx.y;
    const int m = blockIdx.x * 1024 + threadIdx.x;
    const float* src = ct + (long)b * 1024 * 2048 + m;
    unsigned char* sp = spk8 + (long)b * 1024 * 2048 + m;
    unsigned* mw = mask_ws + (long)b * 32 * 2048 + m;
    double v = 0.0;
    for (int tw = 0; tw < 32; tw++) {
        float c[32];
#pragma unroll
        for (int j = 0; j < 32; j++)
            c[j] = src[(long)(tw * 32 + j) * 2048];
        unsigned mword = 0;
#pragma unroll
        for (int j = 0; j < 32; j++) {
            v = 0.95 * v + (double)c[j];
            bool s = v >= 1.0;
            mword |= (s ? 1u : 0u) << j;
            if (s) v = 0.0;
            sp[(long)(tw * 32 + j) * 2048] = s ? 1 : 0;
        }
        mw[(long)tw * 2048] = mword;
    }
}

// masks [b][32][2048] -> f32 spikes [b][2048][1024] (overwrites dead cur1t)
__global__ __launch_bounds__(256) void expand_spk(
    const unsigned* __restrict__ mask_ws,
    float* __restrict__ spk1)
{
    __shared__ unsigned msk[8][32];
    const long rowbase = (long)blockIdx.x * 8;
    const int b = (int)(rowbase >> 11), m0 = (int)(rowbase & 2047);
    const int tid = threadIdx.x;
    {
        int w = tid >> 3, r = tid & 7;
        msk[r][w] = mask_ws[((long)b * 32 + w) * 2048 + m0 + r];
    }
    __syncthreads();
    const int r = tid >> 5, l5 = tid & 31;
    float* dst = spk1 + (rowbase + r) * 1024;
    const int sh = (l5 & 7) * 4;
#pragma unroll
    for (int j = 0; j < 8; j++) {
        const int t = l5 * 4 + j * 128;
        const unsigned w = msk[r][(l5 >> 3) + j * 4];
        float4 o;
        o.x = ((w >> sh) & 1u) ? 1.f : 0.f;
        o.y = ((w >> (sh + 1)) & 1u) ? 1.f : 0.f;
        o.z = ((w >> (sh + 2)) & 1u) ? 1.f : 0.f;
        o.w = ((w >> (sh + 3)) & 1u) ? 1.f : 0.f;
        *(float4*)&dst[t] = o;
    }
}

// LDS-chunked LIF (round 4, kept for layer 2 + fallback tier)
template <int RPB, bool EMIT>
__global__ __launch_bounds__(256) void lif_lds(float* __restrict__ cur,
                                               unsigned char* __restrict__ spk8)
{
    __shared__ float cs[RPB][36];
    const long rowbase = (long)blockIdx.x * RPB;
    float* base = cur + rowbase * 1024;
    const int tid = threadIdx.x;
    const int b = (int)(rowbase >> 11);
    const int m0 = (int)(rowbase & 2047);
    unsigned char* sb = EMIT ? spk8 + (long)b * 1024 * 2048 + m0 : nullptr;
    double v = 0.0;
    const int NV = RPB * 32 / 4;
    for (int tc = 0; tc < 1024; tc += 32) {
        for (int f = tid; f < NV; f += 256) {
            int row = f >> 3, t4 = (f & 7) * 4;
            *(float4*)&cs[row][t4] = *(const float4*)&base[(long)row * 1024 + tc + t4];
        }
        __syncthreads();
        if (tid < RPB) {
#pragma unroll
            for (int j = 0; j < 32; j++) {
                v = 0.95 * v + (double)cs[tid][j];
                bool s = v >= 1.0;
                cs[tid][j] = s ? 1.f : 0.f;
                if (s) v = 0.0;
            }
        }
        __syncthreads();
        for (int f = tid; f < NV; f += 256) {
            int row = f >> 3, t4 = (f & 7) * 4;
            *(float4*)&base[(long)row * 1024 + tc + t4] = *(float4*)&cs[row][t4];
        }
        if (EMIT) {
            const int NQ = 32 * (RPB / 4);
            for (int q = tid; q < NQ; q += 256) {
                int t = q >> (__builtin_ctz(RPB / 4)), mq = q & (RPB / 4 - 1);
                uchar4 u;
                u.x = (unsigned char)cs[mq * 4 + 0][t];
                u.y = (unsigned char)cs[mq * 4 + 1][t];
                u.z = (unsigned char)cs[mq * 4 + 2][t];
                u.w = (unsigned char)cs[mq * 4 + 3][t];
                *(uchar4*)&sb[(long)(tc + t) * 2048 + mq * 4] = u;
            }
        }
        __syncthreads();
    }
}

// ======================= fallback (round 3, proven) =======================

__global__ __launch_bounds__(256) void gemm_f16x3_kernel(
    const float* __restrict__ A, const float* __restrict__ Bmat,
    const float* __restrict__ bias, float* __restrict__ C,
    int M, int N, int K, long sB, long sC)
{
    __shared__ _Float16 As[3][128][40];
    __shared__ _Float16 Bsh[128][40];
    const int batch = blockIdx.z;
    const float* Bp = Bmat + (long)batch * sB;
    float* Cp = C + (long)batch * sC;
    const int m0 = blockIdx.y * 128, n0 = blockIdx.x * 128;
    const int tid = threadIdx.x, lane = tid & 63, wave = tid >> 6;
    const int wrow = (wave >> 1) * 64, wcol = (wave & 1) * 64;
    const int lm = lane & 15, lq = lane >> 4;
    const int a_mo = tid >> 3, a_kc = (tid & 7) * 4;
    const int b_kq = tid >> 5, b_nq = tid & 31;

    f32x4 acc[3][4][4];
#pragma unroll
    for (int p = 0; p < 3; p++)
#pragma unroll
        for (int i = 0; i < 4; i++)
#pragma unroll
            for (int j = 0; j < 4; j++) acc[p][i][j] = (f32x4)0.f;

    for (int k0 = 0; k0 < K; k0 += 32) {
#pragma unroll
        for (int i = 0; i < 4; i++) {
            const int m = i * 32 + a_mo;
            float4 w = *(const float4*)&A[(long)(m0 + m) * K + k0 + a_kc];
            _Float16 a0[4], a1[4], a2[4];
            split3(w.x, a0[0], a1[0], a2[0]);
            split3(w.y, a0[1], a1[1], a2[1]);
            split3(w.z, a0[2], a1[2], a2[2]);
            split3(w.w, a0[3], a1[3], a2[3]);
            *(f16x4*)&As[0][m][a_kc] = (f16x4){a0[0], a0[1], a0[2], a0[3]};
            *(f16x4*)&As[1][m][a_kc] = (f16x4){a1[0], a1[1], a1[2], a1[3]};
            *(f16x4*)&As[2][m][a_kc] = (f16x4){a2[0], a2[1], a2[2], a2[3]};
        }
        {
            float4 r0 = *(const float4*)&Bp[(long)(k0 + b_kq * 4 + 0) * N + n0 + b_nq * 4];
            float4 r1 = *(const float4*)&Bp[(long)(k0 + b_kq * 4 + 1) * N + n0 + b_nq * 4];
            float4 r2 = *(const float4*)&Bp[(long)(k0 + b_kq * 4 + 2) * N + n0 + b_nq * 4];
            float4 r3 = *(const float4*)&Bp[(long)(k0 + b_kq * 4 + 3) * N + n0 + b_nq * 4];
            *(f16x4*)&Bsh[b_nq * 4 + 0][b_kq * 4] =
                (f16x4){(_Float16)r0.x, (_Float16)r1.x, (_Float16)r2.x, (_Float16)r3.x};
            *(f16x4*)&Bsh[b_nq * 4 + 1][b_kq * 4] =
                (f16x4){(_Float16)r0.y, (_Float16)r1.y, (_Float16)r2.y, (_Float16)r3.y};
            *(f16x4*)&Bsh[b_nq * 4 + 2][b_kq * 4] =
                (f16x4){(_Float16)r0.z, (_Float16)r1.z, (_Float16)r2.z, (_Float16)r3.z};
            *(f16x4*)&Bsh[b_nq * 4 + 3][b_kq * 4] =
                (f16x4){(_Float16)r0.w, (_Float16)r1.w, (_Float16)r2.w, (_Float16)r3.w};
        }
        __syncthreads();
        f16x8 bf[4];
#pragma unroll
        for (int j = 0; j < 4; j++)
            bf[j] = *(const f16x8*)&Bsh[wcol + j * 16 + lm][lq * 8];
#pragma unroll
        for (int p = 0; p < 3; p++) {
            f16x8 af[4];
#pragma unroll
            for (int i = 0; i < 4; i++)
                af[i] = *(const f16x8*)&As[p][wrow + i * 16 + lm][lq * 8];
#pragma unroll
            for (int i = 0; i < 4; i++)
#pragma unroll
                for (int j = 0; j < 4; j++)
                    acc[p][i][j] = __builtin_amdgcn_mfma_f32_16x16x32_f16(
                        af[i], bf[j], acc[p][i][j], 0, 0, 0);
        }
        __syncthreads();
    }
#pragma unroll
    for (int i = 0; i < 4; i++) {
#pragma unroll
        for (int r = 0; r < 4; r++) {
            const int row = m0 + wrow + i * 16 + lq * 4 + r;
            const double bv = (double)bias[row];
#pragma unroll
            for (int j = 0; j < 4; j++) {
                double s = (double)acc[0][i][j][r]
                         + (double)acc[1][i][j][r] * 4.8828125e-4
                         + (double)acc[2][i][j][r] * 4.76837158203125e-7 + bv;
                Cp[(long)row * N + n0 + wcol + j * 16 + lm] = (float)s;
            }
        }
    }
}

__global__ __launch_bounds__(256) void lif_rows(float* __restrict__ data,
                                                long nrows, int T)
{
    long r = (long)blockIdx.x * blockDim.x + threadIdx.x;
    if (r >= nrows) return;
    float* p = data + r * (long)T;
    double v = 0.0;
    for (int t = 0; t < T; t += 4) {
        float4 c = *(float4*)(p + t);
        float4 s;
        v = 0.95 * v + (double)c.x; s.x = (v >= 1.0) ? 1.f : 0.f; if (v >= 1.0) v = 0.0;
        v = 0.95 * v + (double)c.y; s.y = (v >= 1.0) ? 1.f : 0.f; if (v >= 1.0) v = 0.0;
        v = 0.95 * v + (double)c.z; s.z = (v >= 1.0) ? 1.f : 0.f; if (v >= 1.0) v = 0.0;
        v = 0.95 * v + (double)c.w; s.w = (v >= 1.0) ? 1.f : 0.f; if (v >= 1.0) v = 0.0;
        *(float4*)(p + t) = s;
    }
}

// ======================= launch =======================

extern "C" void kernel_launch(void* const* d_in, const int* in_sizes, int n_in,
                              void* d_out, int out_size, void* d_ws, size_t ws_size,
                              hipStream_t stream)
{
    const float* x  = (const float*)d_in[0];  // (32, 512, 1024)
    const float* w1 = (const float*)d_in[1];  // (2048, 512)
    const float* b1 = (const float*)d_in[2];  // (2048)
    const float* w2 = (const float*)d_in[3];  // (256, 2048)
    const float* b2 = (const float*)d_in[4];  // (256)

    float* out  = (float*)d_out;
    float* spk1 = out;                              // (32, 2048, 1024)
    float* spk2 = out + (long)32 * 2048 * 1024;     // (32, 256, 1024)

    const size_t WP1 = 6291456;        // [16][3][2048][32] f16
    const size_t WP2 = 3145728;        // [64][3][256][32] f16
    const size_t X8T = 16777216;       // [32][1024][512] i8
    const size_t SPK = 67108864;       // [32][1024][2048] i8
    const size_t MSK = 8388608;        // [32][32][2048] u32
    const size_t NEED_R4 = WP1 + WP2 + X8T + SPK;
    const size_t NEED = NEED_R4 + MSK;

    if (ws_size >= NEED_R4) {
        char* ws = (char*)d_ws;
        _Float16* wp1 = (_Float16*)ws;
        _Float16* wp2 = (_Float16*)(ws + WP1);
        unsigned char* x8t = (unsigned char*)(ws + WP1 + WP2);
        unsigned char* spk8 = (unsigned char*)(ws + WP1 + WP2 + X8T);
        unsigned* mask_ws = (unsigned*)(ws + NEED_R4);

        prep_w<<<512, 256, 0, stream>>>(w1, wp1, 2048, 512);
        prep_w<<<256, 256, 0, stream>>>(w2, wp2, 256, 2048);
        prep_x<<<dim3(16, 8, 32), 256, 0, stream>>>(x, x8t);

        if (ws_size >= NEED) {
            // fast path: transposed cur1 -> coalesced LIF -> mask expansion
            gemm_planes_T<<<dim3(16, 8, 32), 256, 0, stream>>>(
                wp1, x8t, b1, spk1, 2048, 512);
            lif1_t<<<dim3(2, 32), 1024, 0, stream>>>(spk1, spk8, mask_ws);
            expand_spk<<<8192, 256, 0, stream>>>(mask_ws, spk1);
        } else {
            gemm_planes<<<dim3(8, 16, 32), 256, 0, stream>>>(
                wp1, x8t, b1, spk1, 2048, 512);
            lif_lds<256, true><<<256, 256, 0, stream>>>(spk1, spk8);
        }
        gemm_planes<<<dim3(8, 2, 32), 256, 0, stream>>>(wp2, spk8, b2, spk2, 256, 2048);
        lif_lds<128, false><<<64, 256, 0, stream>>>(spk2, nullptr);
    } else {
        gemm_f16x3_kernel<<<dim3(8, 16, 32), 256, 0, stream>>>(
            w1, x, b1, spk1, 2048, 1024, 512, (long)512 * 1024, (long)2048 * 1024);
        lif_rows<<<(65536 + 255) / 256, 256, 0, stream>>>(spk1, 65536, 1024);
        gemm_f16x3_kernel<<<dim3(8, 2, 32), 256, 0, stream>>>(
            w2, spk1, b2, spk2, 256, 1024, 2048, (long)2048 * 1024, (long)256 * 1024);
        lif_rows<<<(8192 + 255) / 256, 256, 0, stream>>>(spk2, 8192, 1024);
    }
}

// Round 6
// 826.341 us; speedup vs baseline: 3.0347x; 1.1149x over previous
//
#include <hip/hip_runtime.h>

// ---------------------------------------------------------------------------
// LavaNetwork, bit-exact 3-plane f16 MFMA GEMM.
// Round-6: bank-conflict-free LDS via chunk XOR swizzle ((row>>1)&3) baked
// into the prep_w global layout (rides through global_load_lds) and applied
// to Bs staging stores/reads; v_perm-based i8->f16 conversion; lif1_t
// re-gridded to 256 blocks. Numerics identical to rounds 3-5 (proven exact).
// ---------------------------------------------------------------------------

typedef _Float16 f16x8 __attribute__((ext_vector_type(8)));
typedef _Float16 f16x4 __attribute__((ext_vector_type(4)));
typedef float f32x4 __attribute__((ext_vector_type(4)));

__device__ inline void split3(float w, _Float16& q0, _Float16& q1, _Float16& q2) {
    float p0 = rintf(w * 4096.f) * 2.44140625e-4f;
    float r1 = w - p0;
    float p1s = rintf(r1 * 8388608.f) * 2.44140625e-4f;
    float r2 = r1 - p1s * 4.8828125e-4f;
    float p2s = rintf(r2 * 1.7179869184e10f) * 1.220703125e-4f;
    q0 = (_Float16)p0;
    q1 = (_Float16)p1s;
    q2 = (_Float16)p2s;
}

#define GLDS(g, l) __builtin_amdgcn_global_load_lds( \
    (const __attribute__((address_space(1))) void*)(g), \
    (__attribute__((address_space(3))) void*)(l), 16, 0, 0)

// {0,1} byte pair -> packed f16 pair via v_perm + mul
__device__ inline unsigned b2h_lo(unsigned w) {
    return __builtin_amdgcn_perm(0u, w, 0x0C010C00u) * 0x3C00u;
}
__device__ inline unsigned b2h_hi(unsigned w) {
    return __builtin_amdgcn_perm(0u, w, 0x0C030C02u) * 0x3C00u;
}

// ======================= prep =======================

// w (M,K) f32 -> wp [K/32][3][M][32] f16 planes, 16B chunks XOR-swizzled by
// ((m>>1)&3) so LDS fragment reads are bank-conflict-free after GLDS staging.
__global__ __launch_bounds__(256) void prep_w(const float* __restrict__ A,
                                              _Float16* __restrict__ wp,
                                              int M, int K)
{
    long gtid = (long)blockIdx.x * 256 + threadIdx.x;
    int K8 = K / 8;
    int m = (int)(gtid / K8), rem = (int)(gtid % K8);
    int kt = rem >> 2, c = rem & 3;
    const float* src = A + (long)m * K + kt * 32 + c * 8;
    float4 wa = *(const float4*)src;
    float4 wb = *(const float4*)(src + 4);
    float wv[8] = {wa.x, wa.y, wa.z, wa.w, wb.x, wb.y, wb.z, wb.w};
    f16x8 v0, v1, v2;
#pragma unroll
    for (int j = 0; j < 8; j++) {
        _Float16 a, b, cq;
        split3(wv[j], a, b, cq);
        v0[j] = a; v1[j] = b; v2[j] = cq;
    }
    const int csw = c ^ ((m >> 1) & 3);   // swizzled chunk slot
    long base = (((long)kt * 3) * M + m) * 32 + csw * 8;
    *(f16x8*)&wp[base] = v0;
    *(f16x8*)&wp[base + (long)M * 32] = v1;
    *(f16x8*)&wp[base + 2L * M * 32] = v2;
}

// x [b][512][1024] f32 -> x8t [b][1024][512] i8 (transpose + binarize)
__global__ __launch_bounds__(256) void prep_x(const float* __restrict__ x,
                                              unsigned char* __restrict__ xt)
{
    __shared__ float xs[64][68];
    const int b = blockIdx.z, i0 = blockIdx.y * 64, t0 = blockIdx.x * 64;
    const float* xb = x + ((long)b * 512 + i0) * 1024 + t0;
#pragma unroll
    for (int p = 0; p < 4; p++) {
        int f = threadIdx.x + p * 256;
        int i = f >> 4, t4 = (f & 15) * 4;
        *(float4*)&xs[i][t4] = *(const float4*)&xb[(long)i * 1024 + t4];
    }
    __syncthreads();
    int tt = threadIdx.x >> 2, c = threadIdx.x & 3;
    unsigned char bytes[16];
#pragma unroll
    for (int j = 0; j < 16; j++)
        bytes[j] = (unsigned char)xs[c * 16 + j][tt];
    *(uint4*)&xt[((long)b * 1024 + t0 + tt) * 512 + i0 + c * 16] = *(uint4*)bytes;
}

// ======================= GEMMs =======================

// C[b][M][1024] = combine3(W @ act) + bias    (row = m, col = t)
__global__ __launch_bounds__(256, 2) void gemm_planes(
    const _Float16* __restrict__ wp,
    const unsigned char* __restrict__ bx,
    const float* __restrict__ bias,
    float* __restrict__ C,
    int M, int K)
{
    __shared__ _Float16 As[2][3][128][32];
    __shared__ _Float16 Bs[2][128][32];

    const int b = blockIdx.z;
    const unsigned char* bxb = bx + (long)b * 1024 * K;
    float* Cp = C + (long)b * M * 1024;
    const int m0 = blockIdx.y * 128, n0 = blockIdx.x * 128;
    const int tid = threadIdx.x, lane = tid & 63, wave = tid >> 6;
    const int wrow = (wave >> 1) * 64, wcol = (wave & 1) * 64;
    const int lm = lane & 15, lq = lane >> 4;
    const int sw = ((lm >> 1) & 3) * 8;          // lane-const chunk swizzle
    const int fo = (lq * 8) ^ sw;                // fragment read offset
    const int bn = tid >> 1, bh = tid & 1;
    const int sB = (bn >> 1) & 3;
    const int bo0 = (((bh * 2) ^ sB) * 8);       // Bs store slots (swizzled)
    const int bo1 = (((bh * 2 + 1) ^ sB) * 8);

    f32x4 acc[3][4][4];
#pragma unroll
    for (int p = 0; p < 3; p++)
#pragma unroll
        for (int i = 0; i < 4; i++)
#pragma unroll
            for (int j = 0; j < 4; j++) acc[p][i][j] = (f32x4)0.f;

    const int niter = K >> 6;
    for (int kt2 = 0; kt2 < niter; kt2++) {
        for (int r = wave; r < 48; r += 4) {
            int sub = r / 24, rp = r % 24, p = rp >> 3, slab = rp & 7;
            int kt = kt2 * 2 + sub;
            const _Float16* g = wp + (((long)kt * 3 + p) * M + m0 + slab * 16) * 32
                                + lane * 8;
            GLDS(g, &As[sub][p][slab * 16][0]);
        }
#pragma unroll
        for (int sub = 0; sub < 2; sub++) {
            int kt = kt2 * 2 + sub;
            uint4 w = *(const uint4*)&bxb[((long)(n0 + bn)) * K + kt * 32 + bh * 16];
            unsigned ww[4] = {w.x, w.y, w.z, w.w};
            unsigned out[8];
#pragma unroll
            for (int u = 0; u < 4; u++) {
                out[u * 2 + 0] = b2h_lo(ww[u]);
                out[u * 2 + 1] = b2h_hi(ww[u]);
            }
            *(uint4*)&Bs[sub][bn][bo0] = *(uint4*)&out[0];
            *(uint4*)&Bs[sub][bn][bo1] = *(uint4*)&out[4];
        }
        __syncthreads();

#pragma unroll
        for (int sub = 0; sub < 2; sub++) {
            f16x8 bf[4];
#pragma unroll
            for (int j = 0; j < 4; j++)
                bf[j] = *(const f16x8*)&Bs[sub][wcol + j * 16 + lm][fo];
#pragma unroll
            for (int p = 0; p < 3; p++) {
                f16x8 af[4];
#pragma unroll
                for (int i = 0; i < 4; i++)
                    af[i] = *(const f16x8*)&As[sub][p][wrow + i * 16 + lm][fo];
#pragma unroll
                for (int i = 0; i < 4; i++)
#pragma unroll
                    for (int j = 0; j < 4; j++)
                        acc[p][i][j] = __builtin_amdgcn_mfma_f32_16x16x32_f16(
                            af[i], bf[j], acc[p][i][j], 0, 0, 0);
            }
        }
        __syncthreads();
    }

#pragma unroll
    for (int i = 0; i < 4; i++) {
#pragma unroll
        for (int r = 0; r < 4; r++) {
            const int row = m0 + wrow + i * 16 + lq * 4 + r;
            const double bv = (double)bias[row];
#pragma unroll
            for (int j = 0; j < 4; j++) {
                double s = (double)acc[0][i][j][r]
                         + (double)acc[1][i][j][r] * 4.8828125e-4
                         + (double)acc[2][i][j][r] * 4.76837158203125e-7
                         + bv;
                Cp[(long)row * 1024 + n0 + wcol + j * 16 + lm] = (float)s;
            }
        }
    }
}

// Transposed variant: Ct[b][t][M] = combine3(act @ W^T) + bias[m]
__global__ __launch_bounds__(256, 2) void gemm_planes_T(
    const _Float16* __restrict__ wp,
    const unsigned char* __restrict__ bx,
    const float* __restrict__ bias,
    float* __restrict__ Ct,
    int M, int K)
{
    __shared__ _Float16 As[2][3][128][32];   // weights [m][k]
    __shared__ _Float16 Bs[2][128][32];      // acts    [t][k]

    const int b = blockIdx.z;
    const unsigned char* bxb = bx + (long)b * 1024 * K;
    float* Cp = Ct + (long)b * 1024 * M;
    const int m0 = blockIdx.x * 128, t0 = blockIdx.y * 128;
    const int tid = threadIdx.x, lane = tid & 63, wave = tid >> 6;
    const int wt = (wave >> 1) * 64, wm = (wave & 1) * 64;
    const int lm = lane & 15, lq = lane >> 4;
    const int sw = ((lm >> 1) & 3) * 8;
    const int fo = (lq * 8) ^ sw;
    const int bn = tid >> 1, bh = tid & 1;
    const int sB = (bn >> 1) & 3;
    const int bo0 = (((bh * 2) ^ sB) * 8);
    const int bo1 = (((bh * 2 + 1) ^ sB) * 8);

    f32x4 acc[3][4][4];   // [plane][t-sub][m-sub]
#pragma unroll
    for (int p = 0; p < 3; p++)
#pragma unroll
        for (int i = 0; i < 4; i++)
#pragma unroll
            for (int j = 0; j < 4; j++) acc[p][i][j] = (f32x4)0.f;

    const int niter = K >> 6;
    for (int kt2 = 0; kt2 < niter; kt2++) {
        for (int r = wave; r < 48; r += 4) {
            int sub = r / 24, rp = r % 24, p = rp >> 3, slab = rp & 7;
            int kt = kt2 * 2 + sub;
            const _Float16* g = wp + (((long)kt * 3 + p) * M + m0 + slab * 16) * 32
                                + lane * 8;
            GLDS(g, &As[sub][p][slab * 16][0]);
        }
#pragma unroll
        for (int sub = 0; sub < 2; sub++) {
            int kt = kt2 * 2 + sub;
            uint4 w = *(const uint4*)&bxb[((long)(t0 + bn)) * K + kt * 32 + bh * 16];
            unsigned ww[4] = {w.x, w.y, w.z, w.w};
            unsigned out[8];
#pragma unroll
            for (int u = 0; u < 4; u++) {
                out[u * 2 + 0] = b2h_lo(ww[u]);
                out[u * 2 + 1] = b2h_hi(ww[u]);
            }
            *(uint4*)&Bs[sub][bn][bo0] = *(uint4*)&out[0];
            *(uint4*)&Bs[sub][bn][bo1] = *(uint4*)&out[4];
        }
        __syncthreads();

#pragma unroll
        for (int sub = 0; sub < 2; sub++) {
            f16x8 af[4];   // activation frags (A operand, t rows)
#pragma unroll
            for (int i = 0; i < 4; i++)
                af[i] = *(const f16x8*)&Bs[sub][wt + i * 16 + lm][fo];
#pragma unroll
            for (int p = 0; p < 3; p++) {
                f16x8 wf[4];   // weight frags (B operand, m cols)
#pragma unroll
                for (int j = 0; j < 4; j++)
                    wf[j] = *(const f16x8*)&As[sub][p][wm + j * 16 + lm][fo];
#pragma unroll
                for (int i = 0; i < 4; i++)
#pragma unroll
                    for (int j = 0; j < 4; j++)
                        acc[p][i][j] = __builtin_amdgcn_mfma_f32_16x16x32_f16(
                            af[i], wf[j], acc[p][i][j], 0, 0, 0);
            }
        }
        __syncthreads();
    }

    double bvj[4];
#pragma unroll
    for (int j = 0; j < 4; j++) bvj[j] = (double)bias[m0 + wm + j * 16 + lm];

#pragma unroll
    for (int i = 0; i < 4; i++) {
#pragma unroll
        for (int r = 0; r < 4; r++) {
            const int trow = t0 + wt + i * 16 + lq * 4 + r;
#pragma unroll
            for (int j = 0; j < 4; j++) {
                double s = (double)acc[0][i][j][r]
                         + (double)acc[1][i][j][r] * 4.8828125e-4
                         + (double)acc[2][i][j][r] * 4.76837158203125e-7
                         + bvj[j];
                Cp[(long)trow * M + m0 + wm + j * 16 + lm] = (float)s;
            }
        }
    }
}

// ======================= LIF =======================

// Coalesced thread-per-row scan over transposed cur [b][1024][2048].
// Emits i8 spikes [b][t][2048] and per-row 1024-bit masks.
__global__ __launch_bounds__(256) void lif1_t(
    const float* __restrict__ ct,
    unsigned char* __restrict__ spk8,
    unsigned* __restrict__ mask_ws)
{
    const int b = blockIdx.y;
    const int m = blockIdx.x * 256 + threadIdx.x;
    const float* src = ct + (long)b * 1024 * 2048 + m;
    unsigned char* sp = spk8 + (long)b * 1024 * 2048 + m;
    unsigned* mw = mask_ws + (long)b * 32 * 2048 + m;
    double v = 0.0;
    for (int tw = 0; tw < 32; tw++) {
        float c[32];
#pragma unroll
        for (int j = 0; j < 32; j++)
            c[j] = src[(long)(tw * 32 + j) * 2048];
        unsigned mword = 0;
#pragma unroll
        for (int j = 0; j < 32; j++) {
            v = 0.95 * v + (double)c[j];
            bool s = v >= 1.0;
            mword |= (s ? 1u : 0u) << j;
            if (s) v = 0.0;
            sp[(long)(tw * 32 + j) * 2048] = s ? 1 : 0;
        }
        mw[(long)tw * 2048] = mword;
    }
}

// masks [b][32][2048] -> f32 spikes [b][2048][1024]
__global__ __launch_bounds__(256) void expand_spk(
    const unsigned* __restrict__ mask_ws,
    float* __restrict__ spk1)
{
    __shared__ unsigned msk[8][32];
    const long rowbase = (long)blockIdx.x * 8;
    const int b = (int)(rowbase >> 11), m0 = (int)(rowbase & 2047);
    const int tid = threadIdx.x;
    {
        int w = tid >> 3, r = tid & 7;
        msk[r][w] = mask_ws[((long)b * 32 + w) * 2048 + m0 + r];
    }
    __syncthreads();
    const int r = tid >> 5, l5 = tid & 31;
    float* dst = spk1 + (rowbase + r) * 1024;
    const int sh = (l5 & 7) * 4;
#pragma unroll
    for (int j = 0; j < 8; j++) {
        const int t = l5 * 4 + j * 128;
        const unsigned w = msk[r][(l5 >> 3) + j * 4];
        float4 o;
        o.x = ((w >> sh) & 1u) ? 1.f : 0.f;
        o.y = ((w >> (sh + 1)) & 1u) ? 1.f : 0.f;
        o.z = ((w >> (sh + 2)) & 1u) ? 1.f : 0.f;
        o.w = ((w >> (sh + 3)) & 1u) ? 1.f : 0.f;
        *(float4*)&dst[t] = o;
    }
}

// LDS-chunked LIF (kept for layer 2 + fallback tier)
template <int RPB, bool EMIT>
__global__ __launch_bounds__(256) void lif_lds(float* __restrict__ cur,
                                               unsigned char* __restrict__ spk8)
{
    __shared__ float cs[RPB][36];
    const long rowbase = (long)blockIdx.x * RPB;
    float* base = cur + rowbase * 1024;
    const int tid = threadIdx.x;
    const int b = (int)(rowbase >> 11);
    const int m0 = (int)(rowbase & 2047);
    unsigned char* sb = EMIT ? spk8 + (long)b * 1024 * 2048 + m0 : nullptr;
    double v = 0.0;
    const int NV = RPB * 32 / 4;
    for (int tc = 0; tc < 1024; tc += 32) {
        for (int f = tid; f < NV; f += 256) {
            int row = f >> 3, t4 = (f & 7) * 4;
            *(float4*)&cs[row][t4] = *(const float4*)&base[(long)row * 1024 + tc + t4];
        }
        __syncthreads();
        if (tid < RPB) {
#pragma unroll
            for (int j = 0; j < 32; j++) {
                v = 0.95 * v + (double)cs[tid][j];
                bool s = v >= 1.0;
                cs[tid][j] = s ? 1.f : 0.f;
                if (s) v = 0.0;
            }
        }
        __syncthreads();
        for (int f = tid; f < NV; f += 256) {
            int row = f >> 3, t4 = (f & 7) * 4;
            *(float4*)&base[(long)row * 1024 + tc + t4] = *(float4*)&cs[row][t4];
        }
        if (EMIT) {
            const int NQ = 32 * (RPB / 4);
            for (int q = tid; q < NQ; q += 256) {
                int t = q >> (__builtin_ctz(RPB / 4)), mq = q & (RPB / 4 - 1);
                uchar4 u;
                u.x = (unsigned char)cs[mq * 4 + 0][t];
                u.y = (unsigned char)cs[mq * 4 + 1][t];
                u.z = (unsigned char)cs[mq * 4 + 2][t];
                u.w = (unsigned char)cs[mq * 4 + 3][t];
                *(uchar4*)&sb[(long)(tc + t) * 2048 + mq * 4] = u;
            }
        }
        __syncthreads();
    }
}

// ======================= fallback (round 3, proven) =======================

__global__ __launch_bounds__(256) void gemm_f16x3_kernel(
    const float* __restrict__ A, const float* __restrict__ Bmat,
    const float* __restrict__ bias, float* __restrict__ C,
    int M, int N, int K, long sB, long sC)
{
    __shared__ _Float16 As[3][128][40];
    __shared__ _Float16 Bsh[128][40];
    const int batch = blockIdx.z;
    const float* Bp = Bmat + (long)batch * sB;
    float* Cp = C + (long)batch * sC;
    const int m0 = blockIdx.y * 128, n0 = blockIdx.x * 128;
    const int tid = threadIdx.x, lane = tid & 63, wave = tid >> 6;
    const int wrow = (wave >> 1) * 64, wcol = (wave & 1) * 64;
    const int lm = lane & 15, lq = lane >> 4;
    const int a_mo = tid >> 3, a_kc = (tid & 7) * 4;
    const int b_kq = tid >> 5, b_nq = tid & 31;

    f32x4 acc[3][4][4];
#pragma unroll
    for (int p = 0; p < 3; p++)
#pragma unroll
        for (int i = 0; i < 4; i++)
#pragma unroll
            for (int j = 0; j < 4; j++) acc[p][i][j] = (f32x4)0.f;

    for (int k0 = 0; k0 < K; k0 += 32) {
#pragma unroll
        for (int i = 0; i < 4; i++) {
            const int m = i * 32 + a_mo;
            float4 w = *(const float4*)&A[(long)(m0 + m) * K + k0 + a_kc];
            _Float16 a0[4], a1[4], a2[4];
            split3(w.x, a0[0], a1[0], a2[0]);
            split3(w.y, a0[1], a1[1], a2[1]);
            split3(w.z, a0[2], a1[2], a2[2]);
            split3(w.w, a0[3], a1[3], a2[3]);
            *(f16x4*)&As[0][m][a_kc] = (f16x4){a0[0], a0[1], a0[2], a0[3]};
            *(f16x4*)&As[1][m][a_kc] = (f16x4){a1[0], a1[1], a1[2], a1[3]};
            *(f16x4*)&As[2][m][a_kc] = (f16x4){a2[0], a2[1], a2[2], a2[3]};
        }
        {
            float4 r0 = *(const float4*)&Bp[(long)(k0 + b_kq * 4 + 0) * N + n0 + b_nq * 4];
            float4 r1 = *(const float4*)&Bp[(long)(k0 + b_kq * 4 + 1) * N + n0 + b_nq * 4];
            float4 r2 = *(const float4*)&Bp[(long)(k0 + b_kq * 4 + 2) * N + n0 + b_nq * 4];
            float4 r3 = *(const float4*)&Bp[(long)(k0 + b_kq * 4 + 3) * N + n0 + b_nq * 4];
            *(f16x4*)&Bsh[b_nq * 4 + 0][b_kq * 4] =
                (f16x4){(_Float16)r0.x, (_Float16)r1.x, (_Float16)r2.x, (_Float16)r3.x};
            *(f16x4*)&Bsh[b_nq * 4 + 1][b_kq * 4] =
                (f16x4){(_Float16)r0.y, (_Float16)r1.y, (_Float16)r2.y, (_Float16)r3.y};
            *(f16x4*)&Bsh[b_nq * 4 + 2][b_kq * 4] =
                (f16x4){(_Float16)r0.z, (_Float16)r1.z, (_Float16)r2.z, (_Float16)r3.z};
            *(f16x4*)&Bsh[b_nq * 4 + 3][b_kq * 4] =
                (f16x4){(_Float16)r0.w, (_Float16)r1.w, (_Float16)r2.w, (_Float16)r3.w};
        }
        __syncthreads();
        f16x8 bf[4];
#pragma unroll
        for (int j = 0; j < 4; j++)
            bf[j] = *(const f16x8*)&Bsh[wcol + j * 16 + lm][lq * 8];
#pragma unroll
        for (int p = 0; p < 3; p++) {
            f16x8 af[4];
#pragma unroll
            for (int i = 0; i < 4; i++)
                af[i] = *(const f16x8*)&As[p][wrow + i * 16 + lm][lq * 8];
#pragma unroll
            for (int i = 0; i < 4; i++)
#pragma unroll
                for (int j = 0; j < 4; j++)
                    acc[p][i][j] = __builtin_amdgcn_mfma_f32_16x16x32_f16(
                        af[i], bf[j], acc[p][i][j], 0, 0, 0);
        }
        __syncthreads();
    }
#pragma unroll
    for (int i = 0; i < 4; i++) {
#pragma unroll
        for (int r = 0; r < 4; r++) {
            const int row = m0 + wrow + i * 16 + lq * 4 + r;
            const double bv = (double)bias[row];
#pragma unroll
            for (int j = 0; j < 4; j++) {
                double s = (double)acc[0][i][j][r]
                         + (double)acc[1][i][j][r] * 4.8828125e-4
                         + (double)acc[2][i][j][r] * 4.76837158203125e-7 + bv;
                Cp[(long)row * N + n0 + wcol + j * 16 + lm] = (float)s;
            }
        }
    }
}

__global__ __launch_bounds__(256) void lif_rows(float* __restrict__ data,
                                                long nrows, int T)
{
    long r = (long)blockIdx.x * blockDim.x + threadIdx.x;
    if (r >= nrows) return;
    float* p = data + r * (long)T;
    double v = 0.0;
    for (int t = 0; t < T; t += 4) {
        float4 c = *(float4*)(p + t);
        float4 s;
        v = 0.95 * v + (double)c.x; s.x = (v >= 1.0) ? 1.f : 0.f; if (v >= 1.0) v = 0.0;
        v = 0.95 * v + (double)c.y; s.y = (v >= 1.0) ? 1.f : 0.f; if (v >= 1.0) v = 0.0;
        v = 0.95 * v + (double)c.z; s.z = (v >= 1.0) ? 1.f : 0.f; if (v >= 1.0) v = 0.0;
        v = 0.95 * v + (double)c.w; s.w = (v >= 1.0) ? 1.f : 0.f; if (v >= 1.0) v = 0.0;
        *(float4*)(p + t) = s;
    }
}

// ======================= launch =======================

extern "C" void kernel_launch(void* const* d_in, const int* in_sizes, int n_in,
                              void* d_out, int out_size, void* d_ws, size_t ws_size,
                              hipStream_t stream)
{
    const float* x  = (const float*)d_in[0];  // (32, 512, 1024)
    const float* w1 = (const float*)d_in[1];  // (2048, 512)
    const float* b1 = (const float*)d_in[2];  // (2048)
    const float* w2 = (const float*)d_in[3];  // (256, 2048)
    const float* b2 = (const float*)d_in[4];  // (256)

    float* out  = (float*)d_out;
    float* spk1 = out;                              // (32, 2048, 1024)
    float* spk2 = out + (long)32 * 2048 * 1024;     // (32, 256, 1024)

    const size_t WP1 = 6291456;        // [16][3][2048][32] f16
    const size_t WP2 = 3145728;        // [64][3][256][32] f16
    const size_t X8T = 16777216;       // [32][1024][512] i8
    const size_t SPK = 67108864;       // [32][1024][2048] i8
    const size_t MSK = 8388608;        // [32][32][2048] u32
    const size_t NEED_R4 = WP1 + WP2 + X8T + SPK;
    const size_t NEED = NEED_R4 + MSK;

    if (ws_size >= NEED_R4) {
        char* ws = (char*)d_ws;
        _Float16* wp1 = (_Float16*)ws;
        _Float16* wp2 = (_Float16*)(ws + WP1);
        unsigned char* x8t = (unsigned char*)(ws + WP1 + WP2);
        unsigned char* spk8 = (unsigned char*)(ws + WP1 + WP2 + X8T);
        unsigned* mask_ws = (unsigned*)(ws + NEED_R4);

        prep_w<<<512, 256, 0, stream>>>(w1, wp1, 2048, 512);
        prep_w<<<256, 256, 0, stream>>>(w2, wp2, 256, 2048);
        prep_x<<<dim3(16, 8, 32), 256, 0, stream>>>(x, x8t);

        if (ws_size >= NEED) {
            gemm_planes_T<<<dim3(16, 8, 32), 256, 0, stream>>>(
                wp1, x8t, b1, spk1, 2048, 512);
            lif1_t<<<dim3(8, 32), 256, 0, stream>>>(spk1, spk8, mask_ws);
            expand_spk<<<8192, 256, 0, stream>>>(mask_ws, spk1);
        } else {
            gemm_planes<<<dim3(8, 16, 32), 256, 0, stream>>>(
                wp1, x8t, b1, spk1, 2048, 512);
            lif_lds<256, true><<<256, 256, 0, stream>>>(spk1, spk8);
        }
        gemm_planes<<<dim3(8, 2, 32), 256, 0, stream>>>(wp2, spk8, b2, spk2, 256, 2048);
        lif_lds<128, false><<<64, 256, 0, stream>>>(spk2, nullptr);
    } else {
        gemm_f16x3_kernel<<<dim3(8, 16, 32), 256, 0, stream>>>(
            w1, x, b1, spk1, 2048, 1024, 512, (long)512 * 1024, (long)2048 * 1024);
        lif_rows<<<(65536 + 255) / 256, 256, 0, stream>>>(spk1, 65536, 1024);
        gemm_f16x3_kernel<<<dim3(8, 2, 32), 256, 0, stream>>>(
            w2, spk1, b2, spk2, 256, 1024, 2048, (long)2048 * 1024, (long)256 * 1024);
        lif_rows<<<(8192 + 255) / 256, 256, 0, stream>>>(spk2, 8192, 1024);
    }
}